// Round 4
// baseline (1546.803 us; speedup 1.0000x reference)
//
#include <hip/hip_runtime.h>

typedef _Float16 f16;
typedef _Float16 half8 __attribute__((ext_vector_type(8)));
typedef float f32x4 __attribute__((ext_vector_type(4)));

#define TOK 49
#define HEADS 8

// XOR swizzle: spreads rows across LDS banks
__device__ __forceinline__ int swzX(int row, int kb) { return row * 1024 + (kb ^ ((row & 7) << 4)); }
__device__ __forceinline__ int swz64(int row, int cb) { return row * 128 + (cb ^ ((row & 7) << 4)); }

// ws layout (f16 elems): wf[16 kc][96 ntile][64 lane][8] at 0 (fragment-ordered
// weights, 1.5MB); QKV[2048 win][24 cb][64][64] at 786432.
#define WT_ELEMS   786432
#define WS_NEED    404226048ull   // (786432 + 201326592) * 2 bytes

// --------- fragment-ordered weight prep: B-frag load = 1 coalesced dwordx4 ----
// wf[((kc*96 + ntile)*64 + lane)*8 + e] = w_m[k*512 + nloc]
//   n = ntile*16 + (lane&15), m = n>>9, nloc = n&511, k = kc*32 + (lane>>4)*8 + e
__global__ void prep_wfrag(const float* __restrict__ wq,
                           const float* __restrict__ wk,
                           const float* __restrict__ wv,
                           f16* __restrict__ wf) {
    int gid = blockIdx.x * 256 + threadIdx.x;   // 0 .. 98303
    int kc   = gid / 6144;
    int rem  = gid % 6144;
    int nt   = rem >> 6;
    int lane = rem & 63;
    int n    = nt * 16 + (lane & 15);
    int m    = n >> 9;
    int nloc = n & 511;
    int k0   = kc * 32 + (lane >> 4) * 8;
    const float* w = (m == 0) ? wq : (m == 1) ? wk : wv;
    alignas(16) f16 vv[8];
    #pragma unroll
    for (int e = 0; e < 8; ++e) vv[e] = (f16)w[(size_t)(k0 + e) * 512 + nloc];
    *(uint4*)(wf + (size_t)gid * 8) = *(const uint4*)vv;
}

// legacy layout for fused fallback: wt[3][512 n][512 k]
__global__ void prep_weights(const float* __restrict__ wq,
                             const float* __restrict__ wk,
                             const float* __restrict__ wv,
                             f16* __restrict__ wt) {
    int gid = blockIdx.x * 256 + threadIdx.x;
    int m   = gid >> 18;
    int rem = gid & 262143;
    int n   = rem >> 9;
    int k   = rem & 511;
    const float* w = (m == 0) ? wq : (m == 1) ? wk : wv;
    wt[gid] = (f16)w[k * 512 + n];
}

// ============================ SPLIT PATH ====================================
// Kernel 1: per-window QKV projection. One barrier-free k-loop (16 chunks of
// BK=32), B-frags streamed coalesced from wf (L2-resident), A-frags from LDS.
// Epilogue stages tiles in LDS then writes pure-coalesced uint4 (no RMW).
__global__ __launch_bounds__(768, 1)
void gemm_qkv(const float* __restrict__ x,
              const float* __restrict__ bqv,
              const float* __restrict__ bkv,
              const float* __restrict__ bvv,
              const f16* __restrict__ wf,
              f16* __restrict__ qkv) {
    __shared__ f16 Xs [50 * 512];   // 51200 B swizzled; row 49 zero
    __shared__ f16 Stg[6 * 4096];   // 49152 B epilogue staging (6 tiles)

    const int win  = blockIdx.x;
    const int bb   = win >> 6;
    const int wy   = (win >> 3) & 7;
    const int wx   = win & 7;
    const int tid  = threadIdx.x;
    const int wave = tid >> 6;        // 0..11; owns cols [wave*128, +128)
    const int lane = tid & 63;
    const int l15  = lane & 15;
    const int lg   = lane >> 4;

    // ---- stage X window -> LDS f16 (swizzled); row 49 zeroed ----
    #pragma unroll
    for (int it = 0; it < 5; ++it) {
        int idx = it * 768 + tid;                 // vec8 slots, 3200 total
        if (idx < 3200) {
            int elem = idx * 8;
            int m = elem >> 9;
            int k = elem & 511;
            uint4 pack = make_uint4(0u, 0u, 0u, 0u);
            if (m < TOK) {
                int i = m / 7, j = m - i * 7;
                const float* src = x + (((size_t)(bb * 56 + wy * 7 + i)) * 56 + (wx * 7 + j)) * 512 + k;
                float4 f0 = ((const float4*)src)[0];
                float4 f1 = ((const float4*)src)[1];
                alignas(16) f16 hh[8] = {(f16)f0.x, (f16)f0.y, (f16)f0.z, (f16)f0.w,
                                         (f16)f1.x, (f16)f1.y, (f16)f1.z, (f16)f1.w};
                pack = *(const uint4*)hh;
            }
            *(uint4*)((char*)Xs + swzX(m, k * 2)) = pack;
        }
    }
    __syncthreads();

    // ---- barrier-free k-loop: acc[nt][mt] = X[64 x 512] . W[512 x 128] ----
    int rowA[4];
    #pragma unroll
    for (int mt = 0; mt < 4; ++mt) {
        int rr = mt * 16 + l15;
        rowA[mt] = (rr < TOK) ? rr : TOK;         // clamp pad rows to zero row
    }
    f32x4 acc[8][4];
    #pragma unroll
    for (int nt = 0; nt < 8; ++nt)
        #pragma unroll
        for (int mt = 0; mt < 4; ++mt)
            acc[nt][mt] = {0.f, 0.f, 0.f, 0.f};

    for (int kc = 0; kc < 16; ++kc) {
        const f16* pb = wf + (((size_t)kc * 96 + wave * 8) * 64 + lane) * 8;
        half8 a[4];
        #pragma unroll
        for (int mt = 0; mt < 4; ++mt)
            a[mt] = *(const half8*)((char*)Xs + swzX(rowA[mt], kc * 64 + lg * 16));
        #pragma unroll
        for (int nt = 0; nt < 8; ++nt) {
            half8 b = *(const half8*)(pb + nt * 512);   // coalesced 1KB/wave
            #pragma unroll
            for (int mt = 0; mt < 4; ++mt)
                acc[nt][mt] = __builtin_amdgcn_mfma_f32_16x16x32_f16(a[mt], b, acc[nt][mt], 0, 0, 0);
        }
    }

    // ---- epilogue: 4 rounds x (3 waves stage 6 tiles in LDS; all copy out) ----
    const int wr  = wave / 3;     // round
    const int wl3 = wave % 3;
    for (int r = 0; r < 4; ++r) {
        if (wr == r) {
            #pragma unroll
            for (int nt = 0; nt < 8; ++nt) {
                const int cbl  = nt >> 2;               // 0/1 within wave
                const int slot = wl3 * 2 + cbl;
                const int cl   = (nt & 3) * 16 + l15;   // in-tile channel
                const int cbg  = 2 * wave + cbl;        // global tile 0..23
                const int mat  = cbg >> 3;
                const float* bias = (mat == 0) ? bqv : (mat == 1) ? bkv : bvv;
                const float bs = bias[(cbg & 7) * 64 + cl];
                if (mat < 2) {
                    #pragma unroll
                    for (int mt = 0; mt < 4; ++mt) {
                        const int t0 = mt * 16 + lg * 4;
                        #pragma unroll
                        for (int rr2 = 0; rr2 < 4; ++rr2)
                            *(f16*)((char*)Stg + slot * 8192 + swz64(t0 + rr2, cl * 2)) =
                                (f16)(acc[nt][mt][rr2] + bs);
                    }
                } else {
                    #pragma unroll
                    for (int mt = 0; mt < 4; ++mt) {
                        const int t0 = mt * 16 + lg * 4;
                        alignas(8) f16 vv[4];
                        #pragma unroll
                        for (int rr2 = 0; rr2 < 4; ++rr2) vv[rr2] = (f16)(acc[nt][mt][rr2] + bs);
                        *(uint2*)((char*)Stg + slot * 8192 + swz64(cl, t0 * 2)) = *(const uint2*)vv;
                    }
                }
            }
        }
        __syncthreads();
        f16* dst = qkv + ((size_t)win * 24 + r * 6) * 4096;
        #pragma unroll
        for (int i = 0; i < 4; ++i) {
            int idx = i * 768 + tid;                    // 3072 uint4
            *(uint4*)(dst + (size_t)idx * 8) = *(const uint4*)((char*)Stg + idx * 16);
        }
        __syncthreads();
    }
}

// Kernel 2: one wave per (window, head). Stage Q/K/Vt tiles to LDS, then
// S = QK^T, softmax (eye-masked), O = PV, fp32 out.
__global__ __launch_bounds__(64)
void attn(const f16* __restrict__ qkv,
          const float* __restrict__ pos_bias,
          float* __restrict__ out) {
    __shared__ f16 Qs [64 * 64];   // Q, then reused for P
    __shared__ f16 Ks [64 * 64];
    __shared__ f16 Vts[64 * 64];

    const int blk  = blockIdx.x;          // win*8 + head
    const int win  = blk >> 3;
    const int head = blk & 7;
    const int lane = threadIdx.x;
    const int l15  = lane & 15;
    const int lg   = lane >> 4;

    const f16* gQ = qkv + ((size_t)win * 24 + head) * 4096;
    const f16* gK = gQ + 8 * 4096;
    const f16* gV = gQ + 16 * 4096;

    #pragma unroll
    for (int i = 0; i < 8; ++i) {
        uint4 q4 = *(const uint4*)(gQ + i * 512 + lane * 8);
        uint4 k4 = *(const uint4*)(gK + i * 512 + lane * 8);
        uint4 v4 = *(const uint4*)(gV + i * 512 + lane * 8);
        *(uint4*)((char*)Qs  + i * 1024 + lane * 16) = q4;
        *(uint4*)((char*)Ks  + i * 1024 + lane * 16) = k4;
        *(uint4*)((char*)Vts + i * 1024 + lane * 16) = v4;
    }
    __syncthreads();

    const float scale = 0.044194173824159216f;   // 1/sqrt(512)
    const float* pb = pos_bias + head * TOK * TOK;

    // preload all Q A-frags (Qs is then dead -> reuse as P)
    half8 qa[4][2];
    #pragma unroll
    for (int mt = 0; mt < 4; ++mt)
        #pragma unroll
        for (int ks = 0; ks < 2; ++ks)
            qa[mt][ks] = *(const half8*)((char*)Qs + swz64(mt * 16 + l15, (ks * 32 + lg * 8) * 2));

    #pragma unroll
    for (int mt = 0; mt < 4; ++mt) {
        f32x4 sacc[4];
        #pragma unroll
        for (int nt = 0; nt < 4; ++nt) sacc[nt] = {0.f, 0.f, 0.f, 0.f};
        #pragma unroll
        for (int nt = 0; nt < 4; ++nt) {
            #pragma unroll
            for (int ks = 0; ks < 2; ++ks) {
                half8 kb = *(const half8*)((char*)Ks + swz64(nt * 16 + l15, (ks * 32 + lg * 8) * 2));
                sacc[nt] = __builtin_amdgcn_mfma_f32_16x16x32_f16(qa[mt][ks], kb, sacc[nt], 0, 0, 0);
            }
        }
        #pragma unroll
        for (int r = 0; r < 4; ++r) {
            const int q  = mt * 16 + lg * 4 + r;
            const int qp = (q < TOK) ? q : 0;
            float sv[4];
            float rmax = -3.4028235e38f;
            #pragma unroll
            for (int nt = 0; nt < 4; ++nt) {
                const int t2 = nt * 16 + l15;
                const int tp = (t2 < TOK) ? t2 : 0;
                float s = sacc[nt][r] * scale + pb[qp * TOK + tp];
                const bool valid = (q < TOK) && (t2 < TOK) && (t2 != q);
                s = valid ? s : -3.4028235e38f;   // eye-mask = finfo.min semantics
                sv[nt] = s;
                rmax = fmaxf(rmax, s);
            }
            #pragma unroll
            for (int md = 1; md < 16; md <<= 1)
                rmax = fmaxf(rmax, __shfl_xor(rmax, md));
            float rsum = 0.f;
            #pragma unroll
            for (int nt = 0; nt < 4; ++nt) {
                float e = __expf(sv[nt] - rmax);
                sv[nt] = e;
                rsum += e;
            }
            #pragma unroll
            for (int md = 1; md < 16; md <<= 1)
                rsum += __shfl_xor(rsum, md);
            const float inv = 1.f / rsum;
            #pragma unroll
            for (int nt = 0; nt < 4; ++nt)
                *(f16*)((char*)Qs + swz64(q, (nt * 16 + l15) * 2)) = (f16)(sv[nt] * inv);
        }
    }

    // ---- O = P V ----
    #pragma unroll
    for (int mt = 0; mt < 4; ++mt) {
        half8 pa[2];
        #pragma unroll
        for (int ks = 0; ks < 2; ++ks)
            pa[ks] = *(const half8*)((char*)Qs + swz64(mt * 16 + l15, (ks * 32 + lg * 8) * 2));
        f32x4 oacc[4];
        #pragma unroll
        for (int ct = 0; ct < 4; ++ct) oacc[ct] = {0.f, 0.f, 0.f, 0.f};
        #pragma unroll
        for (int ct = 0; ct < 4; ++ct) {
            #pragma unroll
            for (int ks = 0; ks < 2; ++ks) {
                half8 vb = *(const half8*)((char*)Vts + swz64(ct * 16 + l15, (ks * 32 + lg * 8) * 2));
                oacc[ct] = __builtin_amdgcn_mfma_f32_16x16x32_f16(pa[ks], vb, oacc[ct], 0, 0, 0);
            }
        }
        #pragma unroll
        for (int r = 0; r < 4; ++r) {
            const int q = mt * 16 + lg * 4 + r;
            if (q < TOK) {
                #pragma unroll
                for (int ct = 0; ct < 4; ++ct)
                    out[((size_t)win * TOK + q) * 512 + head * 64 + ct * 16 + l15] = oacc[ct][r];
            }
        }
    }
}

// ============================ FUSED FALLBACK ================================
__global__ __launch_bounds__(512, 4)
void swin_attn(const float* __restrict__ x,
               const float* __restrict__ bqv,
               const float* __restrict__ bkv,
               const float* __restrict__ bvv,
               const float* __restrict__ pos_bias,
               const f16* __restrict__ wt,
               float* __restrict__ out) {
    __shared__ f16 Xs [50 * 512];
    __shared__ f16 QPs[64 * 64];
    __shared__ f16 Ks [64 * 64];
    __shared__ f16 Vts[64 * 64];

    const int w    = blockIdx.x;
    const int bb   = w >> 6;
    const int wy   = (w >> 3) & 7;
    const int wx   = w & 7;
    const int tid  = threadIdx.x;
    const int wave = tid >> 6;
    const int lane = tid & 63;
    const int l15  = lane & 15;
    const int lg   = lane >> 4;
    const int mh   = wave & 1;
    const int wi   = wave >> 1;

    #pragma unroll
    for (int it = 0; it < 7; ++it) {
        int idx = it * 512 + tid;
        int elem = idx * 8;
        if (elem < 50 * 512) {
            int m = elem >> 9;
            int k = elem & 511;
            uint4 pack = make_uint4(0u, 0u, 0u, 0u);
            if (m < TOK) {
                int i = m / 7, j = m - i * 7;
                const float* src = x + (((size_t)(bb * 56 + wy * 7 + i)) * 56 + (wx * 7 + j)) * 512 + k;
                float4 f0 = ((const float4*)src)[0];
                float4 f1 = ((const float4*)src)[1];
                alignas(16) f16 hh[8] = {(f16)f0.x, (f16)f0.y, (f16)f0.z, (f16)f0.w,
                                         (f16)f1.x, (f16)f1.y, (f16)f1.z, (f16)f1.w};
                pack = *(const uint4*)hh;
            }
            *(uint4*)((char*)Xs + swzX(m, k * 2)) = pack;
        }
    }
    __syncthreads();

    const float scale = 0.044194173824159216f;

    for (int h = 0; h < HEADS; ++h) {
        f32x4 aQ[2], aK[2], aV[2];
        #pragma unroll
        for (int mt = 0; mt < 2; ++mt) {
            aQ[mt] = {0.f, 0.f, 0.f, 0.f};
            aK[mt] = {0.f, 0.f, 0.f, 0.f};
            aV[mt] = {0.f, 0.f, 0.f, 0.f};
        }
        const int ncol = h * 64 + wi * 16 + l15;
        const f16* pQ = wt + (size_t)(ncol) * 512;
        const f16* pK = wt + (size_t)(512 + ncol) * 512;
        const f16* pV = wt + (size_t)(1024 + ncol) * 512;
        const int r0 = mh * 32 + l15;
        const int r1 = mh * 32 + 16 + l15;
        const int rp0 = (r0 < TOK) ? r0 : 49;
        const int rp1 = (r1 < TOK) ? r1 : 49;
        #pragma unroll
        for (int ks = 0; ks < 16; ++ks) {
            const int kk = ks * 32 + lg * 8;
            half8 a0 = *(const half8*)((char*)Xs + swzX(rp0, kk * 2));
            half8 a1 = *(const half8*)((char*)Xs + swzX(rp1, kk * 2));
            half8 fQ = *(const half8*)(pQ + kk);
            half8 fK = *(const half8*)(pK + kk);
            half8 fV = *(const half8*)(pV + kk);
            aQ[0] = __builtin_amdgcn_mfma_f32_16x16x32_f16(a0, fQ, aQ[0], 0, 0, 0);
            aQ[1] = __builtin_amdgcn_mfma_f32_16x16x32_f16(a1, fQ, aQ[1], 0, 0, 0);
            aK[0] = __builtin_amdgcn_mfma_f32_16x16x32_f16(a0, fK, aK[0], 0, 0, 0);
            aK[1] = __builtin_amdgcn_mfma_f32_16x16x32_f16(a1, fK, aK[1], 0, 0, 0);
            aV[0] = __builtin_amdgcn_mfma_f32_16x16x32_f16(a0, fV, aV[0], 0, 0, 0);
            aV[1] = __builtin_amdgcn_mfma_f32_16x16x32_f16(a1, fV, aV[1], 0, 0, 0);
        }

        const float biasQ = bqv[ncol];
        const float biasK = bkv[ncol];
        const float biasV = bvv[ncol];
        const int nloc = wi * 16 + l15;
        #pragma unroll
        for (int mt = 0; mt < 2; ++mt) {
            const int m0 = mh * 32 + mt * 16 + lg * 4;
            #pragma unroll
            for (int r = 0; r < 4; ++r) {
                *(f16*)((char*)QPs + swz64(m0 + r, nloc * 2)) = (f16)(aQ[mt][r] + biasQ);
                *(f16*)((char*)Ks  + swz64(m0 + r, nloc * 2)) = (f16)(aK[mt][r] + biasK);
            }
            alignas(8) f16 vv[4];
            #pragma unroll
            for (int r = 0; r < 4; ++r) vv[r] = (f16)(aV[mt][r] + biasV);
            *(uint2*)((char*)Vts + swz64(nloc, m0 * 2)) = *(const uint2*)vv;
        }
        __syncthreads();

        if (wave < 4) {
            f32x4 sacc[4];
            #pragma unroll
            for (int nt = 0; nt < 4; ++nt) sacc[nt] = {0.f, 0.f, 0.f, 0.f};
            half8 qa[2];
            #pragma unroll
            for (int ks = 0; ks < 2; ++ks)
                qa[ks] = *(const half8*)((char*)QPs + swz64(wave * 16 + l15, (ks * 32 + lg * 8) * 2));
            #pragma unroll
            for (int nt = 0; nt < 4; ++nt) {
                #pragma unroll
                for (int ks = 0; ks < 2; ++ks) {
                    half8 kb = *(const half8*)((char*)Ks + swz64(nt * 16 + l15, (ks * 32 + lg * 8) * 2));
                    sacc[nt] = __builtin_amdgcn_mfma_f32_16x16x32_f16(qa[ks], kb, sacc[nt], 0, 0, 0);
                }
            }
            const float* pb = pos_bias + h * TOK * TOK;
            #pragma unroll
            for (int r = 0; r < 4; ++r) {
                const int q  = wave * 16 + lg * 4 + r;
                const int qp = (q < TOK) ? q : 0;
                float sv[4];
                float rmax = -3.4028235e38f;
                #pragma unroll
                for (int nt = 0; nt < 4; ++nt) {
                    const int t2 = nt * 16 + l15;
                    const int tp = (t2 < TOK) ? t2 : 0;
                    float s = sacc[nt][r] * scale + pb[qp * TOK + tp];
                    const bool valid = (q < TOK) && (t2 < TOK) && (t2 != q);
                    s = valid ? s : -3.4028235e38f;
                    sv[nt] = s;
                    rmax = fmaxf(rmax, s);
                }
                #pragma unroll
                for (int md = 1; md < 16; md <<= 1)
                    rmax = fmaxf(rmax, __shfl_xor(rmax, md));
                float rsum = 0.f;
                #pragma unroll
                for (int nt = 0; nt < 4; ++nt) {
                    float e = __expf(sv[nt] - rmax);
                    sv[nt] = e;
                    rsum += e;
                }
                #pragma unroll
                for (int md = 1; md < 16; md <<= 1)
                    rsum += __shfl_xor(rsum, md);
                const float inv = 1.f / rsum;
                #pragma unroll
                for (int nt = 0; nt < 4; ++nt)
                    *(f16*)((char*)QPs + swz64(q, (nt * 16 + l15) * 2)) = (f16)(sv[nt] * inv);
            }
        }
        __syncthreads();

        {
            const int pmt = wave >> 1;
            const int pnh = wave & 1;
            f32x4 oacc[2];
            oacc[0] = {0.f, 0.f, 0.f, 0.f};
            oacc[1] = {0.f, 0.f, 0.f, 0.f};
            half8 pa[2];
            #pragma unroll
            for (int ks = 0; ks < 2; ++ks)
                pa[ks] = *(const half8*)((char*)QPs + swz64(pmt * 16 + l15, (ks * 32 + lg * 8) * 2));
            #pragma unroll
            for (int nt2 = 0; nt2 < 2; ++nt2) {
                const int nt = pnh * 2 + nt2;
                #pragma unroll
                for (int ks = 0; ks < 2; ++ks) {
                    half8 vb = *(const half8*)((char*)Vts + swz64(nt * 16 + l15, (ks * 32 + lg * 8) * 2));
                    oacc[nt2] = __builtin_amdgcn_mfma_f32_16x16x32_f16(pa[ks], vb, oacc[nt2], 0, 0, 0);
                }
            }
            #pragma unroll
            for (int r = 0; r < 4; ++r) {
                const int q = pmt * 16 + lg * 4 + r;
                if (q < TOK) {
                    #pragma unroll
                    for (int nt2 = 0; nt2 < 2; ++nt2)
                        out[((size_t)w * TOK + q) * 512 + h * 64 + (pnh * 2 + nt2) * 16 + l15] = oacc[nt2][r];
                }
            }
        }
        __syncthreads();
    }
}

extern "C" void kernel_launch(void* const* d_in, const int* in_sizes, int n_in,
                              void* d_out, int out_size, void* d_ws, size_t ws_size,
                              hipStream_t stream) {
    const float* x  = (const float*)d_in[0];
    const float* wq = (const float*)d_in[1];
    const float* bq = (const float*)d_in[2];
    const float* wk = (const float*)d_in[3];
    const float* bk = (const float*)d_in[4];
    const float* wv = (const float*)d_in[5];
    const float* bv = (const float*)d_in[6];
    const float* pb = (const float*)d_in[7];
    f16*   wbuf = (f16*)d_ws;
    float* out  = (float*)d_out;

    if (ws_size >= WS_NEED) {
        f16* qkv = wbuf + WT_ELEMS;
        prep_wfrag<<<384, 256, 0, stream>>>(wq, wk, wv, wbuf);
        gemm_qkv<<<2048, 768, 0, stream>>>(x, bq, bk, bv, wbuf, qkv);
        attn<<<16384, 64, 0, stream>>>(qkv, pb, out);
    } else {
        prep_weights<<<3072, 256, 0, stream>>>(wq, wk, wv, wbuf);
        swin_attn<<<2048, 512, 0, stream>>>(x, bq, bk, bv, pb, wbuf, out);
    }
}

// Round 5
// 1247.015 us; speedup vs baseline: 1.2404x; 1.2404x over previous
//
#include <hip/hip_runtime.h>

typedef _Float16 f16;
typedef _Float16 half8 __attribute__((ext_vector_type(8)));
typedef float f32x4 __attribute__((ext_vector_type(4)));

#define TOK 49
#define HEADS 8

// XOR swizzle: spreads rows across LDS banks
__device__ __forceinline__ int swzX(int row, int kb) { return row * 1024 + (kb ^ ((row & 7) << 4)); }
__device__ __forceinline__ int swz64(int row, int cb) { return row * 128 + (cb ^ ((row & 7) << 4)); }

// ws layout (f16 elems): wf[16 kc][96 ntile][64 lane][8] at 0 (fragment-ordered
// weights, 1.5MB); QKV[2048 win][24 cb][64][64] at 786432.
#define WT_ELEMS   786432
#define WS_NEED    404226048ull   // (786432 + 201326592) * 2 bytes

// --------- fragment-ordered weight prep: B-frag load = 1 coalesced dwordx4 ----
// wf[((kc*96 + ntile)*64 + lane)*8 + e] = w_m[k*512 + nloc]
//   n = ntile*16 + (lane&15), m = n>>9, nloc = n&511, k = kc*32 + (lane>>4)*8 + e
__global__ void prep_wfrag(const float* __restrict__ wq,
                           const float* __restrict__ wk,
                           const float* __restrict__ wv,
                           f16* __restrict__ wf) {
    int gid = blockIdx.x * 256 + threadIdx.x;   // 0 .. 98303
    int kc   = gid / 6144;
    int rem  = gid % 6144;
    int nt   = rem >> 6;
    int lane = rem & 63;
    int n    = nt * 16 + (lane & 15);
    int m    = n >> 9;
    int nloc = n & 511;
    int k0   = kc * 32 + (lane >> 4) * 8;
    const float* w = (m == 0) ? wq : (m == 1) ? wk : wv;
    alignas(16) f16 vv[8];
    #pragma unroll
    for (int e = 0; e < 8; ++e) vv[e] = (f16)w[(size_t)(k0 + e) * 512 + nloc];
    *(uint4*)(wf + (size_t)gid * 8) = *(const uint4*)vv;
}

// legacy layout for fused fallback: wt[3][512 n][512 k]
__global__ void prep_weights(const float* __restrict__ wq,
                             const float* __restrict__ wk,
                             const float* __restrict__ wv,
                             f16* __restrict__ wt) {
    int gid = blockIdx.x * 256 + threadIdx.x;
    int m   = gid >> 18;
    int rem = gid & 262143;
    int n   = rem >> 9;
    int k   = rem & 511;
    const float* w = (m == 0) ? wq : (m == 1) ? wk : wv;
    wt[gid] = (f16)w[k * 512 + n];
}

// ============================ SPLIT PATH ====================================
// Kernel 1: per-window QKV projection. 8 waves, wave does 3 passes of one
// 64-col tile: acc[4][4] (64 VGPR, spill-proof), B-frags coalesced from wf
// with register double-buffer, A-frags from LDS. Epilogue: wave-PRIVATE LDS
// staging slot (no barrier) -> linear readback -> coalesced uint4 stores.
__global__ __launch_bounds__(512, 2)
void gemm_qkv(const float* __restrict__ x,
              const float* __restrict__ bqv,
              const float* __restrict__ bkv,
              const float* __restrict__ bvv,
              const f16* __restrict__ wf,
              f16* __restrict__ qkv) {
    __shared__ f16 Xs [50 * 512];   // 50KB swizzled; row 49 zero
    __shared__ f16 Stg[8 * 4096];   // 64KB: one private 8KB tile slot per wave

    const int win  = blockIdx.x;
    const int bb   = win >> 6;
    const int wy   = (win >> 3) & 7;
    const int wx   = win & 7;
    const int tid  = threadIdx.x;
    const int wave = tid >> 6;        // 0..7
    const int lane = tid & 63;
    const int l15  = lane & 15;
    const int lg   = lane >> 4;

    // ---- stage X window -> LDS f16 (swizzled); row 49 zeroed ----
    #pragma unroll
    for (int it = 0; it < 7; ++it) {
        int idx = it * 512 + tid;                 // vec8 slots, 3200 total
        if (idx < 3200) {
            int elem = idx * 8;
            int m = elem >> 9;
            int k = elem & 511;
            uint4 pack = make_uint4(0u, 0u, 0u, 0u);
            if (m < TOK) {
                int i = m / 7, j = m - i * 7;
                const float* src = x + (((size_t)(bb * 56 + wy * 7 + i)) * 56 + (wx * 7 + j)) * 512 + k;
                float4 f0 = ((const float4*)src)[0];
                float4 f1 = ((const float4*)src)[1];
                alignas(16) f16 hh[8] = {(f16)f0.x, (f16)f0.y, (f16)f0.z, (f16)f0.w,
                                         (f16)f1.x, (f16)f1.y, (f16)f1.z, (f16)f1.w};
                pack = *(const uint4*)hh;
            }
            *(uint4*)((char*)Xs + swzX(m, k * 2)) = pack;
        }
    }
    __syncthreads();

    int rowA[4];
    #pragma unroll
    for (int mt = 0; mt < 4; ++mt) {
        int rr = mt * 16 + l15;
        rowA[mt] = (rr < TOK) ? rr : TOK;         // clamp pad rows to zero row 49
    }
    f16* stg = Stg + wave * 4096;                 // wave-private staging slot

    for (int p = 0; p < 3; ++p) {
        const int cb  = wave * 3 + p;             // tile 0..23
        const int mat = cb >> 3;                  // 0=Q 1=K 2=V

        f32x4 acc[4][4];                          // [nt][mt]
        #pragma unroll
        for (int nt = 0; nt < 4; ++nt)
            #pragma unroll
            for (int mt = 0; mt < 4; ++mt)
                acc[nt][mt] = {0.f, 0.f, 0.f, 0.f};

        // B-frag base: elems ((kc*96 + cb*4 + j)*64 + lane)*8
        const f16* pb0 = wf + ((size_t)(cb * 4) * 64 + lane) * 8;
        half8 b[4], bn[4];
        #pragma unroll
        for (int j = 0; j < 4; ++j)
            b[j] = *(const half8*)(pb0 + j * 512);

        for (int kc = 0; kc < 16; ++kc) {
            if (kc < 15) {
                const f16* pn = pb0 + (size_t)(kc + 1) * 49152;
                #pragma unroll
                for (int j = 0; j < 4; ++j)
                    bn[j] = *(const half8*)(pn + j * 512);
            }
            half8 a[4];
            #pragma unroll
            for (int mt = 0; mt < 4; ++mt)
                a[mt] = *(const half8*)((char*)Xs + swzX(rowA[mt], kc * 64 + lg * 16));
            #pragma unroll
            for (int nt = 0; nt < 4; ++nt)
                #pragma unroll
                for (int mt = 0; mt < 4; ++mt)
                    acc[nt][mt] = __builtin_amdgcn_mfma_f32_16x16x32_f16(a[mt], b[nt], acc[nt][mt], 0, 0, 0);
            #pragma unroll
            for (int j = 0; j < 4; ++j) b[j] = bn[j];
        }

        // ---- epilogue: stage swizzled tile in private slot, no barrier ----
        const float* bias = (mat == 0) ? bqv : (mat == 1) ? bkv : bvv;
        #pragma unroll
        for (int nt = 0; nt < 4; ++nt) {
            const int cl = nt * 16 + l15;                 // in-tile channel
            const float bs = bias[(cb & 7) * 64 + cl];
            if (mat < 2) {
                #pragma unroll
                for (int mt = 0; mt < 4; ++mt) {
                    const int t0 = mt * 16 + lg * 4;
                    #pragma unroll
                    for (int r = 0; r < 4; ++r)
                        *(f16*)((char*)stg + swz64(t0 + r, cl * 2)) = (f16)(acc[nt][mt][r] + bs);
                }
            } else {
                #pragma unroll
                for (int mt = 0; mt < 4; ++mt) {
                    const int t0 = mt * 16 + lg * 4;
                    alignas(8) f16 vv[4];
                    #pragma unroll
                    for (int r = 0; r < 4; ++r) vv[r] = (f16)(acc[nt][mt][r] + bs);
                    *(uint2*)((char*)stg + swz64(cl, t0 * 2)) = *(const uint2*)vv;  // transposed
                }
            }
        }
        // linear readback -> fully coalesced stores (byte-image of the tile)
        f16* dst = qkv + ((size_t)win * 24 + cb) * 4096;
        #pragma unroll
        for (int i = 0; i < 8; ++i)
            *(uint4*)(dst + i * 512 + lane * 8) = *(const uint4*)(stg + i * 512 + lane * 8);
    }
}

// Kernel 2: one wave per (window, head). Stage Q/K/Vt tiles to LDS, then
// S = QK^T, softmax (eye-masked), O = PV, fp32 out.
__global__ __launch_bounds__(64)
void attn(const f16* __restrict__ qkv,
          const float* __restrict__ pos_bias,
          float* __restrict__ out) {
    __shared__ f16 Qs [64 * 64];   // Q, then reused for P
    __shared__ f16 Ks [64 * 64];
    __shared__ f16 Vts[64 * 64];

    const int blk  = blockIdx.x;          // win*8 + head
    const int win  = blk >> 3;
    const int head = blk & 7;
    const int lane = threadIdx.x;
    const int l15  = lane & 15;
    const int lg   = lane >> 4;

    const f16* gQ = qkv + ((size_t)win * 24 + head) * 4096;
    const f16* gK = gQ + 8 * 4096;
    const f16* gV = gQ + 16 * 4096;

    #pragma unroll
    for (int i = 0; i < 8; ++i) {
        uint4 q4 = *(const uint4*)(gQ + i * 512 + lane * 8);
        uint4 k4 = *(const uint4*)(gK + i * 512 + lane * 8);
        uint4 v4 = *(const uint4*)(gV + i * 512 + lane * 8);
        *(uint4*)((char*)Qs  + i * 1024 + lane * 16) = q4;
        *(uint4*)((char*)Ks  + i * 1024 + lane * 16) = k4;
        *(uint4*)((char*)Vts + i * 1024 + lane * 16) = v4;
    }
    __syncthreads();

    const float scale = 0.044194173824159216f;   // 1/sqrt(512)
    const float* pb = pos_bias + head * TOK * TOK;

    // preload all Q A-frags (Qs is then dead -> reuse as P)
    half8 qa[4][2];
    #pragma unroll
    for (int mt = 0; mt < 4; ++mt)
        #pragma unroll
        for (int ks = 0; ks < 2; ++ks)
            qa[mt][ks] = *(const half8*)((char*)Qs + swz64(mt * 16 + l15, (ks * 32 + lg * 8) * 2));

    #pragma unroll
    for (int mt = 0; mt < 4; ++mt) {
        f32x4 sacc[4];
        #pragma unroll
        for (int nt = 0; nt < 4; ++nt) sacc[nt] = {0.f, 0.f, 0.f, 0.f};
        #pragma unroll
        for (int nt = 0; nt < 4; ++nt) {
            #pragma unroll
            for (int ks = 0; ks < 2; ++ks) {
                half8 kb = *(const half8*)((char*)Ks + swz64(nt * 16 + l15, (ks * 32 + lg * 8) * 2));
                sacc[nt] = __builtin_amdgcn_mfma_f32_16x16x32_f16(qa[mt][ks], kb, sacc[nt], 0, 0, 0);
            }
        }
        #pragma unroll
        for (int r = 0; r < 4; ++r) {
            const int q  = mt * 16 + lg * 4 + r;
            const int qp = (q < TOK) ? q : 0;
            float sv[4];
            float rmax = -3.4028235e38f;
            #pragma unroll
            for (int nt = 0; nt < 4; ++nt) {
                const int t2 = nt * 16 + l15;
                const int tp = (t2 < TOK) ? t2 : 0;
                float s = sacc[nt][r] * scale + pb[qp * TOK + tp];
                const bool valid = (q < TOK) && (t2 < TOK) && (t2 != q);
                s = valid ? s : -3.4028235e38f;   // eye-mask = finfo.min semantics
                sv[nt] = s;
                rmax = fmaxf(rmax, s);
            }
            #pragma unroll
            for (int md = 1; md < 16; md <<= 1)
                rmax = fmaxf(rmax, __shfl_xor(rmax, md));
            float rsum = 0.f;
            #pragma unroll
            for (int nt = 0; nt < 4; ++nt) {
                float e = __expf(sv[nt] - rmax);
                sv[nt] = e;
                rsum += e;
            }
            #pragma unroll
            for (int md = 1; md < 16; md <<= 1)
                rsum += __shfl_xor(rsum, md);
            const float inv = 1.f / rsum;
            #pragma unroll
            for (int nt = 0; nt < 4; ++nt)
                *(f16*)((char*)Qs + swz64(q, (nt * 16 + l15) * 2)) = (f16)(sv[nt] * inv);
        }
    }

    // ---- O = P V ----
    #pragma unroll
    for (int mt = 0; mt < 4; ++mt) {
        half8 pa[2];
        #pragma unroll
        for (int ks = 0; ks < 2; ++ks)
            pa[ks] = *(const half8*)((char*)Qs + swz64(mt * 16 + l15, (ks * 32 + lg * 8) * 2));
        f32x4 oacc[4];
        #pragma unroll
        for (int ct = 0; ct < 4; ++ct) oacc[ct] = {0.f, 0.f, 0.f, 0.f};
        #pragma unroll
        for (int ct = 0; ct < 4; ++ct) {
            #pragma unroll
            for (int ks = 0; ks < 2; ++ks) {
                half8 vb = *(const half8*)((char*)Vts + swz64(ct * 16 + l15, (ks * 32 + lg * 8) * 2));
                oacc[ct] = __builtin_amdgcn_mfma_f32_16x16x32_f16(pa[ks], vb, oacc[ct], 0, 0, 0);
            }
        }
        #pragma unroll
        for (int r = 0; r < 4; ++r) {
            const int q = mt * 16 + lg * 4 + r;
            if (q < TOK) {
                #pragma unroll
                for (int ct = 0; ct < 4; ++ct)
                    out[((size_t)win * TOK + q) * 512 + head * 64 + ct * 16 + l15] = oacc[ct][r];
            }
        }
    }
}

// ============================ FUSED FALLBACK ================================
__global__ __launch_bounds__(512, 4)
void swin_attn(const float* __restrict__ x,
               const float* __restrict__ bqv,
               const float* __restrict__ bkv,
               const float* __restrict__ bvv,
               const float* __restrict__ pos_bias,
               const f16* __restrict__ wt,
               float* __restrict__ out) {
    __shared__ f16 Xs [50 * 512];
    __shared__ f16 QPs[64 * 64];
    __shared__ f16 Ks [64 * 64];
    __shared__ f16 Vts[64 * 64];

    const int w    = blockIdx.x;
    const int bb   = w >> 6;
    const int wy   = (w >> 3) & 7;
    const int wx   = w & 7;
    const int tid  = threadIdx.x;
    const int wave = tid >> 6;
    const int lane = tid & 63;
    const int l15  = lane & 15;
    const int lg   = lane >> 4;
    const int mh   = wave & 1;
    const int wi   = wave >> 1;

    #pragma unroll
    for (int it = 0; it < 7; ++it) {
        int idx = it * 512 + tid;
        int elem = idx * 8;
        if (elem < 50 * 512) {
            int m = elem >> 9;
            int k = elem & 511;
            uint4 pack = make_uint4(0u, 0u, 0u, 0u);
            if (m < TOK) {
                int i = m / 7, j = m - i * 7;
                const float* src = x + (((size_t)(bb * 56 + wy * 7 + i)) * 56 + (wx * 7 + j)) * 512 + k;
                float4 f0 = ((const float4*)src)[0];
                float4 f1 = ((const float4*)src)[1];
                alignas(16) f16 hh[8] = {(f16)f0.x, (f16)f0.y, (f16)f0.z, (f16)f0.w,
                                         (f16)f1.x, (f16)f1.y, (f16)f1.z, (f16)f1.w};
                pack = *(const uint4*)hh;
            }
            *(uint4*)((char*)Xs + swzX(m, k * 2)) = pack;
        }
    }
    __syncthreads();

    const float scale = 0.044194173824159216f;

    for (int h = 0; h < HEADS; ++h) {
        f32x4 aQ[2], aK[2], aV[2];
        #pragma unroll
        for (int mt = 0; mt < 2; ++mt) {
            aQ[mt] = {0.f, 0.f, 0.f, 0.f};
            aK[mt] = {0.f, 0.f, 0.f, 0.f};
            aV[mt] = {0.f, 0.f, 0.f, 0.f};
        }
        const int ncol = h * 64 + wi * 16 + l15;
        const f16* pQ = wt + (size_t)(ncol) * 512;
        const f16* pK = wt + (size_t)(512 + ncol) * 512;
        const f16* pV = wt + (size_t)(1024 + ncol) * 512;
        const int r0 = mh * 32 + l15;
        const int r1 = mh * 32 + 16 + l15;
        const int rp0 = (r0 < TOK) ? r0 : 49;
        const int rp1 = (r1 < TOK) ? r1 : 49;
        #pragma unroll
        for (int ks = 0; ks < 16; ++ks) {
            const int kk = ks * 32 + lg * 8;
            half8 a0 = *(const half8*)((char*)Xs + swzX(rp0, kk * 2));
            half8 a1 = *(const half8*)((char*)Xs + swzX(rp1, kk * 2));
            half8 fQ = *(const half8*)(pQ + kk);
            half8 fK = *(const half8*)(pK + kk);
            half8 fV = *(const half8*)(pV + kk);
            aQ[0] = __builtin_amdgcn_mfma_f32_16x16x32_f16(a0, fQ, aQ[0], 0, 0, 0);
            aQ[1] = __builtin_amdgcn_mfma_f32_16x16x32_f16(a1, fQ, aQ[1], 0, 0, 0);
            aK[0] = __builtin_amdgcn_mfma_f32_16x16x32_f16(a0, fK, aK[0], 0, 0, 0);
            aK[1] = __builtin_amdgcn_mfma_f32_16x16x32_f16(a1, fK, aK[1], 0, 0, 0);
            aV[0] = __builtin_amdgcn_mfma_f32_16x16x32_f16(a0, fV, aV[0], 0, 0, 0);
            aV[1] = __builtin_amdgcn_mfma_f32_16x16x32_f16(a1, fV, aV[1], 0, 0, 0);
        }

        const float biasQ = bqv[ncol];
        const float biasK = bkv[ncol];
        const float biasV = bvv[ncol];
        const int nloc = wi * 16 + l15;
        #pragma unroll
        for (int mt = 0; mt < 2; ++mt) {
            const int m0 = mh * 32 + mt * 16 + lg * 4;
            #pragma unroll
            for (int r = 0; r < 4; ++r) {
                *(f16*)((char*)QPs + swz64(m0 + r, nloc * 2)) = (f16)(aQ[mt][r] + biasQ);
                *(f16*)((char*)Ks  + swz64(m0 + r, nloc * 2)) = (f16)(aK[mt][r] + biasK);
            }
            alignas(8) f16 vv[4];
            #pragma unroll
            for (int r = 0; r < 4; ++r) vv[r] = (f16)(aV[mt][r] + biasV);
            *(uint2*)((char*)Vts + swz64(nloc, m0 * 2)) = *(const uint2*)vv;
        }
        __syncthreads();

        if (wave < 4) {
            f32x4 sacc[4];
            #pragma unroll
            for (int nt = 0; nt < 4; ++nt) sacc[nt] = {0.f, 0.f, 0.f, 0.f};
            half8 qa[2];
            #pragma unroll
            for (int ks = 0; ks < 2; ++ks)
                qa[ks] = *(const half8*)((char*)QPs + swz64(wave * 16 + l15, (ks * 32 + lg * 8) * 2));
            #pragma unroll
            for (int nt = 0; nt < 4; ++nt) {
                #pragma unroll
                for (int ks = 0; ks < 2; ++ks) {
                    half8 kb = *(const half8*)((char*)Ks + swz64(nt * 16 + l15, (ks * 32 + lg * 8) * 2));
                    sacc[nt] = __builtin_amdgcn_mfma_f32_16x16x32_f16(qa[ks], kb, sacc[nt], 0, 0, 0);
                }
            }
            const float* pb = pos_bias + h * TOK * TOK;
            #pragma unroll
            for (int r = 0; r < 4; ++r) {
                const int q  = wave * 16 + lg * 4 + r;
                const int qp = (q < TOK) ? q : 0;
                float sv[4];
                float rmax = -3.4028235e38f;
                #pragma unroll
                for (int nt = 0; nt < 4; ++nt) {
                    const int t2 = nt * 16 + l15;
                    const int tp = (t2 < TOK) ? t2 : 0;
                    float s = sacc[nt][r] * scale + pb[qp * TOK + tp];
                    const bool valid = (q < TOK) && (t2 < TOK) && (t2 != q);
                    s = valid ? s : -3.4028235e38f;
                    sv[nt] = s;
                    rmax = fmaxf(rmax, s);
                }
                #pragma unroll
                for (int md = 1; md < 16; md <<= 1)
                    rmax = fmaxf(rmax, __shfl_xor(rmax, md));
                float rsum = 0.f;
                #pragma unroll
                for (int nt = 0; nt < 4; ++nt) {
                    float e = __expf(sv[nt] - rmax);
                    sv[nt] = e;
                    rsum += e;
                }
                #pragma unroll
                for (int md = 1; md < 16; md <<= 1)
                    rsum += __shfl_xor(rsum, md);
                const float inv = 1.f / rsum;
                #pragma unroll
                for (int nt = 0; nt < 4; ++nt)
                    *(f16*)((char*)QPs + swz64(q, (nt * 16 + l15) * 2)) = (f16)(sv[nt] * inv);
            }
        }
        __syncthreads();

        {
            const int pmt = wave >> 1;
            const int pnh = wave & 1;
            f32x4 oacc[2];
            oacc[0] = {0.f, 0.f, 0.f, 0.f};
            oacc[1] = {0.f, 0.f, 0.f, 0.f};
            half8 pa[2];
            #pragma unroll
            for (int ks = 0; ks < 2; ++ks)
                pa[ks] = *(const half8*)((char*)QPs + swz64(pmt * 16 + l15, (ks * 32 + lg * 8) * 2));
            #pragma unroll
            for (int nt2 = 0; nt2 < 2; ++nt2) {
                const int nt = pnh * 2 + nt2;
                #pragma unroll
                for (int ks = 0; ks < 2; ++ks) {
                    half8 vb = *(const half8*)((char*)Vts + swz64(nt * 16 + l15, (ks * 32 + lg * 8) * 2));
                    oacc[nt2] = __builtin_amdgcn_mfma_f32_16x16x32_f16(pa[ks], vb, oacc[nt2], 0, 0, 0);
                }
            }
            #pragma unroll
            for (int r = 0; r < 4; ++r) {
                const int q = pmt * 16 + lg * 4 + r;
                if (q < TOK) {
                    #pragma unroll
                    for (int nt2 = 0; nt2 < 2; ++nt2)
                        out[((size_t)w * TOK + q) * 512 + h * 64 + (pnh * 2 + nt2) * 16 + l15] = oacc[nt2][r];
                }
            }
        }
        __syncthreads();
    }
}

extern "C" void kernel_launch(void* const* d_in, const int* in_sizes, int n_in,
                              void* d_out, int out_size, void* d_ws, size_t ws_size,
                              hipStream_t stream) {
    const float* x  = (const float*)d_in[0];
    const float* wq = (const float*)d_in[1];
    const float* bq = (const float*)d_in[2];
    const float* wk = (const float*)d_in[3];
    const float* bk = (const float*)d_in[4];
    const float* wv = (const float*)d_in[5];
    const float* bv = (const float*)d_in[6];
    const float* pb = (const float*)d_in[7];
    f16*   wbuf = (f16*)d_ws;
    float* out  = (float*)d_out;

    if (ws_size >= WS_NEED) {
        f16* qkv = wbuf + WT_ELEMS;
        prep_wfrag<<<384, 256, 0, stream>>>(wq, wk, wv, wbuf);
        gemm_qkv<<<2048, 512, 0, stream>>>(x, bq, bk, bv, wbuf, qkv);
        attn<<<16384, 64, 0, stream>>>(qkv, pb, out);
    } else {
        prep_weights<<<3072, 256, 0, stream>>>(wq, wk, wv, wbuf);
        swin_attn<<<2048, 512, 0, stream>>>(x, bq, bk, bv, pb, wbuf, out);
    }
}

// Round 6
// 1198.102 us; speedup vs baseline: 1.2910x; 1.0408x over previous
//
#include <hip/hip_runtime.h>

typedef _Float16 f16;
typedef _Float16 half8 __attribute__((ext_vector_type(8)));
typedef float f32x4 __attribute__((ext_vector_type(4)));

#define TOK 49
#define HEADS 8

// XOR swizzle: spreads rows across LDS banks
__device__ __forceinline__ int swzX(int row, int kb) { return row * 1024 + (kb ^ ((row & 7) << 4)); }
__device__ __forceinline__ int swz64(int row, int cb) { return row * 128 + (cb ^ ((row & 7) << 4)); }

// ws layout (f16 elems): wf[16 kc][96 ntile][64 lane][8] at 0 (fragment-ordered
// weights, 1.5MB); QKV[2048 win][24 cb][64][64] PLAIN row-major at 786432.
// Q/K tiles: [tok][ch]; V tiles transposed: [ch][tok].
#define WT_ELEMS   786432
#define WS_NEED    404226048ull   // (786432 + 201326592) * 2 bytes

// --------- fragment-ordered weight prep: B-frag load = 1 coalesced dwordx4 ----
// wf[((kc*96 + ntile)*64 + lane)*8 + e] = w_m[k*512 + nloc]
//   n = ntile*16 + (lane&15), m = n>>9, nloc = n&511, k = kc*32 + (lane>>4)*8 + e
__global__ void prep_wfrag(const float* __restrict__ wq,
                           const float* __restrict__ wk,
                           const float* __restrict__ wv,
                           f16* __restrict__ wf) {
    int gid = blockIdx.x * 256 + threadIdx.x;   // 0 .. 98303
    int kc   = gid / 6144;
    int rem  = gid % 6144;
    int nt   = rem >> 6;
    int lane = rem & 63;
    int n    = nt * 16 + (lane & 15);
    int m    = n >> 9;
    int nloc = n & 511;
    int k0   = kc * 32 + (lane >> 4) * 8;
    const float* w = (m == 0) ? wq : (m == 1) ? wk : wv;
    alignas(16) f16 vv[8];
    #pragma unroll
    for (int e = 0; e < 8; ++e) vv[e] = (f16)w[(size_t)(k0 + e) * 512 + nloc];
    *(uint4*)(wf + (size_t)gid * 8) = *(const uint4*)vv;
}

// legacy layout for fused fallback: wt[3][512 n][512 k]
__global__ void prep_weights(const float* __restrict__ wq,
                             const float* __restrict__ wk,
                             const float* __restrict__ wv,
                             f16* __restrict__ wt) {
    int gid = blockIdx.x * 256 + threadIdx.x;
    int m   = gid >> 18;
    int rem = gid & 262143;
    int n   = rem >> 9;
    int k   = rem & 511;
    const float* w = (m == 0) ? wq : (m == 1) ? wk : wv;
    wt[gid] = (f16)w[k * 512 + n];
}

// ============================ SPLIT PATH ====================================
// Kernel 1: per-window QKV projection. 8 waves x 3 passes of one 64-col tile;
// acc[4][4], 2-deep register prefetch of coalesced B-frags; wave-private LDS
// staging (swizzled) -> XOR-unswizzle readback -> PLAIN coalesced stores.
// launch_bounds(512,1): VGPR cap ~256 -> no spill (R5 lesson: needs ~150).
__global__ __launch_bounds__(512, 1)
void gemm_qkv(const float* __restrict__ x,
              const float* __restrict__ bqv,
              const float* __restrict__ bkv,
              const float* __restrict__ bvv,
              const f16* __restrict__ wf,
              f16* __restrict__ qkv) {
    __shared__ f16 Xs [50 * 512];   // 50KB swizzled; row 49 zero
    __shared__ f16 Stg[8 * 4096];   // 64KB: one private 8KB tile slot per wave

    const int win  = blockIdx.x;
    const int bb   = win >> 6;
    const int wy   = (win >> 3) & 7;
    const int wx   = win & 7;
    const int tid  = threadIdx.x;
    const int wave = tid >> 6;        // 0..7
    const int lane = tid & 63;
    const int l15  = lane & 15;
    const int lg   = lane >> 4;

    // ---- stage X window -> LDS f16 (swizzled); row 49 zeroed ----
    #pragma unroll
    for (int it = 0; it < 7; ++it) {
        int idx = it * 512 + tid;                 // vec8 slots, 3200 total
        if (idx < 3200) {
            int elem = idx * 8;
            int m = elem >> 9;
            int k = elem & 511;
            uint4 pack = make_uint4(0u, 0u, 0u, 0u);
            if (m < TOK) {
                int i = m / 7, j = m - i * 7;
                const float* src = x + (((size_t)(bb * 56 + wy * 7 + i)) * 56 + (wx * 7 + j)) * 512 + k;
                float4 f0 = ((const float4*)src)[0];
                float4 f1 = ((const float4*)src)[1];
                alignas(16) f16 hh[8] = {(f16)f0.x, (f16)f0.y, (f16)f0.z, (f16)f0.w,
                                         (f16)f1.x, (f16)f1.y, (f16)f1.z, (f16)f1.w};
                pack = *(const uint4*)hh;
            }
            *(uint4*)((char*)Xs + swzX(m, k * 2)) = pack;
        }
    }
    __syncthreads();

    int rowA[4];
    #pragma unroll
    for (int mt = 0; mt < 4; ++mt) {
        int rr = mt * 16 + l15;
        rowA[mt] = (rr < TOK) ? rr : TOK;         // clamp pad rows to zero row 49
    }
    f16* stg = Stg + wave * 4096;                 // wave-private staging slot

    for (int p = 0; p < 3; ++p) {
        const int cb  = wave * 3 + p;             // tile 0..23
        const int mat = cb >> 3;                  // 0=Q 1=K 2=V

        f32x4 acc[4][4];                          // [nt][mt]
        #pragma unroll
        for (int nt = 0; nt < 4; ++nt)
            #pragma unroll
            for (int mt = 0; mt < 4; ++mt)
                acc[nt][mt] = {0.f, 0.f, 0.f, 0.f};

        // B-frag base: elems ((kc*96 + cb*4 + j)*64 + lane)*8; kc stride 49152
        const f16* pb0 = wf + ((size_t)(cb * 4) * 64 + lane) * 8;
        half8 bA[4], bB[4];
        #pragma unroll
        for (int j = 0; j < 4; ++j) bA[j] = *(const half8*)(pb0 + j * 512);
        #pragma unroll
        for (int j = 0; j < 4; ++j) bB[j] = *(const half8*)(pb0 + 49152 + j * 512);

        #pragma unroll
        for (int kc2 = 0; kc2 < 8; ++kc2) {
            const int kc = kc2 * 2;
            {   // even step: consume bA, prefetch kc+2 into bA
                half8 a[4];
                #pragma unroll
                for (int mt = 0; mt < 4; ++mt)
                    a[mt] = *(const half8*)((char*)Xs + swzX(rowA[mt], kc * 64 + lg * 16));
                #pragma unroll
                for (int nt = 0; nt < 4; ++nt)
                    #pragma unroll
                    for (int mt = 0; mt < 4; ++mt)
                        acc[nt][mt] = __builtin_amdgcn_mfma_f32_16x16x32_f16(a[mt], bA[nt], acc[nt][mt], 0, 0, 0);
                if (kc + 2 < 16) {
                    const f16* pn = pb0 + (size_t)(kc + 2) * 49152;
                    #pragma unroll
                    for (int j = 0; j < 4; ++j) bA[j] = *(const half8*)(pn + j * 512);
                }
            }
            {   // odd step: consume bB, prefetch kc+3 into bB
                half8 a[4];
                #pragma unroll
                for (int mt = 0; mt < 4; ++mt)
                    a[mt] = *(const half8*)((char*)Xs + swzX(rowA[mt], (kc + 1) * 64 + lg * 16));
                #pragma unroll
                for (int nt = 0; nt < 4; ++nt)
                    #pragma unroll
                    for (int mt = 0; mt < 4; ++mt)
                        acc[nt][mt] = __builtin_amdgcn_mfma_f32_16x16x32_f16(a[mt], bB[nt], acc[nt][mt], 0, 0, 0);
                if (kc + 3 < 16) {
                    const f16* pn = pb0 + (size_t)(kc + 3) * 49152;
                    #pragma unroll
                    for (int j = 0; j < 4; ++j) bB[j] = *(const half8*)(pn + j * 512);
                }
            }
        }

        // ---- epilogue: stage swizzled tile in private slot (no barrier) ----
        const float* bias = (mat == 0) ? bqv : (mat == 1) ? bkv : bvv;
        #pragma unroll
        for (int nt = 0; nt < 4; ++nt) {
            const int cl = nt * 16 + l15;                 // in-tile channel
            const float bs = bias[(cb & 7) * 64 + cl];
            if (mat < 2) {
                #pragma unroll
                for (int mt = 0; mt < 4; ++mt) {
                    const int t0 = mt * 16 + lg * 4;
                    #pragma unroll
                    for (int r = 0; r < 4; ++r)
                        *(f16*)((char*)stg + swz64(t0 + r, cl * 2)) = (f16)(acc[nt][mt][r] + bs);
                }
            } else {
                #pragma unroll
                for (int mt = 0; mt < 4; ++mt) {
                    const int t0 = mt * 16 + lg * 4;
                    alignas(8) f16 vv[4];
                    #pragma unroll
                    for (int r = 0; r < 4; ++r) vv[r] = (f16)(acc[nt][mt][r] + bs);
                    *(uint2*)((char*)stg + swz64(cl, t0 * 2)) = *(const uint2*)vv;  // transposed
                }
            }
        }
        // XOR-unswizzle readback -> PLAIN row-major tile, fully coalesced stores
        f16* dst = qkv + ((size_t)win * 24 + cb) * 4096;
        #pragma unroll
        for (int i = 0; i < 8; ++i) {
            int chunk = i * 64 + lane;                    // 0..511 (16B chunks)
            int row   = chunk >> 3;
            int c16   = (chunk & 7) * 16;
            uint4 v = *(const uint4*)((char*)stg + row * 128 + (c16 ^ ((row & 7) << 4)));
            *(uint4*)(dst + (size_t)chunk * 8) = v;
        }
    }
}

// Kernel 2: one wave per (window, head). PLAIN tiles -> all Q/K/V MFMA frags
// load DIRECT from global (coalesced 64B sectors, each tile read once).
// LDS only holds P (8KB) -> high occupancy.
__global__ __launch_bounds__(64)
void attn(const f16* __restrict__ qkv,
          const float* __restrict__ pos_bias,
          float* __restrict__ out) {
    __shared__ f16 Ps[64 * 64];    // 8KB

    const int blk  = blockIdx.x;          // win*8 + head
    const int win  = blk >> 3;
    const int head = blk & 7;
    const int lane = threadIdx.x;
    const int l15  = lane & 15;
    const int lg   = lane >> 4;

    const f16* gQ = qkv + ((size_t)win * 24 + head) * 4096;
    const f16* gK = gQ + 8 * 4096;
    const f16* gV = gQ + 16 * 4096;

    const float scale = 0.044194173824159216f;   // 1/sqrt(512)
    const float* pb = pos_bias + head * TOK * TOK;

    // direct global frag loads: lane l15 -> row, lg*8 -> col chunk
    half8 qa[4][2], kb[4][2];
    #pragma unroll
    for (int mt = 0; mt < 4; ++mt)
        #pragma unroll
        for (int ks = 0; ks < 2; ++ks)
            qa[mt][ks] = *(const half8*)(gQ + (mt * 16 + l15) * 64 + ks * 32 + lg * 8);
    #pragma unroll
    for (int nt = 0; nt < 4; ++nt)
        #pragma unroll
        for (int ks = 0; ks < 2; ++ks)
            kb[nt][ks] = *(const half8*)(gK + (nt * 16 + l15) * 64 + ks * 32 + lg * 8);

    #pragma unroll
    for (int mt = 0; mt < 4; ++mt) {
        f32x4 sacc[4];
        #pragma unroll
        for (int nt = 0; nt < 4; ++nt) sacc[nt] = {0.f, 0.f, 0.f, 0.f};
        #pragma unroll
        for (int nt = 0; nt < 4; ++nt)
            #pragma unroll
            for (int ks = 0; ks < 2; ++ks)
                sacc[nt] = __builtin_amdgcn_mfma_f32_16x16x32_f16(qa[mt][ks], kb[nt][ks], sacc[nt], 0, 0, 0);

        #pragma unroll
        for (int r = 0; r < 4; ++r) {
            const int q  = mt * 16 + lg * 4 + r;
            const int qp = (q < TOK) ? q : 0;
            float sv[4];
            float rmax = -3.4028235e38f;
            #pragma unroll
            for (int nt = 0; nt < 4; ++nt) {
                const int t2 = nt * 16 + l15;
                const int tp = (t2 < TOK) ? t2 : 0;
                float s = sacc[nt][r] * scale + pb[qp * TOK + tp];
                const bool valid = (q < TOK) && (t2 < TOK) && (t2 != q);
                s = valid ? s : -3.4028235e38f;   // eye-mask = finfo.min semantics
                sv[nt] = s;
                rmax = fmaxf(rmax, s);
            }
            #pragma unroll
            for (int md = 1; md < 16; md <<= 1)
                rmax = fmaxf(rmax, __shfl_xor(rmax, md));
            float rsum = 0.f;
            #pragma unroll
            for (int nt = 0; nt < 4; ++nt) {
                float e = __expf(sv[nt] - rmax);
                sv[nt] = e;
                rsum += e;
            }
            #pragma unroll
            for (int md = 1; md < 16; md <<= 1)
                rsum += __shfl_xor(rsum, md);
            const float inv = 1.f / rsum;
            #pragma unroll
            for (int nt = 0; nt < 4; ++nt)
                *(f16*)((char*)Ps + swz64(q, (nt * 16 + l15) * 2)) = (f16)(sv[nt] * inv);
        }
    }

    // ---- O = P V : V^T frags direct from global (kb registers now dead) ----
    half8 vb[4][2];
    #pragma unroll
    for (int ct = 0; ct < 4; ++ct)
        #pragma unroll
        for (int ks = 0; ks < 2; ++ks)
            vb[ct][ks] = *(const half8*)(gV + (ct * 16 + l15) * 64 + ks * 32 + lg * 8);

    #pragma unroll
    for (int mt = 0; mt < 4; ++mt) {
        half8 pa[2];
        #pragma unroll
        for (int ks = 0; ks < 2; ++ks)
            pa[ks] = *(const half8*)((char*)Ps + swz64(mt * 16 + l15, (ks * 32 + lg * 8) * 2));
        f32x4 oacc[4];
        #pragma unroll
        for (int ct = 0; ct < 4; ++ct) oacc[ct] = {0.f, 0.f, 0.f, 0.f};
        #pragma unroll
        for (int ct = 0; ct < 4; ++ct)
            #pragma unroll
            for (int ks = 0; ks < 2; ++ks)
                oacc[ct] = __builtin_amdgcn_mfma_f32_16x16x32_f16(pa[ks], vb[ct][ks], oacc[ct], 0, 0, 0);
        #pragma unroll
        for (int r = 0; r < 4; ++r) {
            const int q = mt * 16 + lg * 4 + r;
            if (q < TOK) {
                #pragma unroll
                for (int ct = 0; ct < 4; ++ct)
                    out[((size_t)win * TOK + q) * 512 + head * 64 + ct * 16 + l15] = oacc[ct][r];
            }
        }
    }
}

// ============================ FUSED FALLBACK ================================
__global__ __launch_bounds__(512, 4)
void swin_attn(const float* __restrict__ x,
               const float* __restrict__ bqv,
               const float* __restrict__ bkv,
               const float* __restrict__ bvv,
               const float* __restrict__ pos_bias,
               const f16* __restrict__ wt,
               float* __restrict__ out) {
    __shared__ f16 Xs [50 * 512];
    __shared__ f16 QPs[64 * 64];
    __shared__ f16 Ks [64 * 64];
    __shared__ f16 Vts[64 * 64];

    const int w    = blockIdx.x;
    const int bb   = w >> 6;
    const int wy   = (w >> 3) & 7;
    const int wx   = w & 7;
    const int tid  = threadIdx.x;
    const int wave = tid >> 6;
    const int lane = tid & 63;
    const int l15  = lane & 15;
    const int lg   = lane >> 4;
    const int mh   = wave & 1;
    const int wi   = wave >> 1;

    #pragma unroll
    for (int it = 0; it < 7; ++it) {
        int idx = it * 512 + tid;
        int elem = idx * 8;
        if (elem < 50 * 512) {
            int m = elem >> 9;
            int k = elem & 511;
            uint4 pack = make_uint4(0u, 0u, 0u, 0u);
            if (m < TOK) {
                int i = m / 7, j = m - i * 7;
                const float* src = x + (((size_t)(bb * 56 + wy * 7 + i)) * 56 + (wx * 7 + j)) * 512 + k;
                float4 f0 = ((const float4*)src)[0];
                float4 f1 = ((const float4*)src)[1];
                alignas(16) f16 hh[8] = {(f16)f0.x, (f16)f0.y, (f16)f0.z, (f16)f0.w,
                                         (f16)f1.x, (f16)f1.y, (f16)f1.z, (f16)f1.w};
                pack = *(const uint4*)hh;
            }
            *(uint4*)((char*)Xs + swzX(m, k * 2)) = pack;
        }
    }
    __syncthreads();

    const float scale = 0.044194173824159216f;

    for (int h = 0; h < HEADS; ++h) {
        f32x4 aQ[2], aK[2], aV[2];
        #pragma unroll
        for (int mt = 0; mt < 2; ++mt) {
            aQ[mt] = {0.f, 0.f, 0.f, 0.f};
            aK[mt] = {0.f, 0.f, 0.f, 0.f};
            aV[mt] = {0.f, 0.f, 0.f, 0.f};
        }
        const int ncol = h * 64 + wi * 16 + l15;
        const f16* pQ = wt + (size_t)(ncol) * 512;
        const f16* pK = wt + (size_t)(512 + ncol) * 512;
        const f16* pV = wt + (size_t)(1024 + ncol) * 512;
        const int r0 = mh * 32 + l15;
        const int r1 = mh * 32 + 16 + l15;
        const int rp0 = (r0 < TOK) ? r0 : 49;
        const int rp1 = (r1 < TOK) ? r1 : 49;
        #pragma unroll
        for (int ks = 0; ks < 16; ++ks) {
            const int kk = ks * 32 + lg * 8;
            half8 a0 = *(const half8*)((char*)Xs + swzX(rp0, kk * 2));
            half8 a1 = *(const half8*)((char*)Xs + swzX(rp1, kk * 2));
            half8 fQ = *(const half8*)(pQ + kk);
            half8 fK = *(const half8*)(pK + kk);
            half8 fV = *(const half8*)(pV + kk);
            aQ[0] = __builtin_amdgcn_mfma_f32_16x16x32_f16(a0, fQ, aQ[0], 0, 0, 0);
            aQ[1] = __builtin_amdgcn_mfma_f32_16x16x32_f16(a1, fQ, aQ[1], 0, 0, 0);
            aK[0] = __builtin_amdgcn_mfma_f32_16x16x32_f16(a0, fK, aK[0], 0, 0, 0);
            aK[1] = __builtin_amdgcn_mfma_f32_16x16x32_f16(a1, fK, aK[1], 0, 0, 0);
            aV[0] = __builtin_amdgcn_mfma_f32_16x16x32_f16(a0, fV, aV[0], 0, 0, 0);
            aV[1] = __builtin_amdgcn_mfma_f32_16x16x32_f16(a1, fV, aV[1], 0, 0, 0);
        }

        const float biasQ = bqv[ncol];
        const float biasK = bkv[ncol];
        const float biasV = bvv[ncol];
        const int nloc = wi * 16 + l15;
        #pragma unroll
        for (int mt = 0; mt < 2; ++mt) {
            const int m0 = mh * 32 + mt * 16 + lg * 4;
            #pragma unroll
            for (int r = 0; r < 4; ++r) {
                *(f16*)((char*)QPs + swz64(m0 + r, nloc * 2)) = (f16)(aQ[mt][r] + biasQ);
                *(f16*)((char*)Ks  + swz64(m0 + r, nloc * 2)) = (f16)(aK[mt][r] + biasK);
            }
            alignas(8) f16 vv[4];
            #pragma unroll
            for (int r = 0; r < 4; ++r) vv[r] = (f16)(aV[mt][r] + biasV);
            *(uint2*)((char*)Vts + swz64(nloc, m0 * 2)) = *(const uint2*)vv;
        }
        __syncthreads();

        if (wave < 4) {
            f32x4 sacc[4];
            #pragma unroll
            for (int nt = 0; nt < 4; ++nt) sacc[nt] = {0.f, 0.f, 0.f, 0.f};
            half8 qa[2];
            #pragma unroll
            for (int ks = 0; ks < 2; ++ks)
                qa[ks] = *(const half8*)((char*)QPs + swz64(wave * 16 + l15, (ks * 32 + lg * 8) * 2));
            #pragma unroll
            for (int nt = 0; nt < 4; ++nt) {
                #pragma unroll
                for (int ks = 0; ks < 2; ++ks) {
                    half8 kb = *(const half8*)((char*)Ks + swz64(nt * 16 + l15, (ks * 32 + lg * 8) * 2));
                    sacc[nt] = __builtin_amdgcn_mfma_f32_16x16x32_f16(qa[ks], kb, sacc[nt], 0, 0, 0);
                }
            }
            const float* pb = pos_bias + h * TOK * TOK;
            #pragma unroll
            for (int r = 0; r < 4; ++r) {
                const int q  = wave * 16 + lg * 4 + r;
                const int qp = (q < TOK) ? q : 0;
                float sv[4];
                float rmax = -3.4028235e38f;
                #pragma unroll
                for (int nt = 0; nt < 4; ++nt) {
                    const int t2 = nt * 16 + l15;
                    const int tp = (t2 < TOK) ? t2 : 0;
                    float s = sacc[nt][r] * scale + pb[qp * TOK + tp];
                    const bool valid = (q < TOK) && (t2 < TOK) && (t2 != q);
                    s = valid ? s : -3.4028235e38f;
                    sv[nt] = s;
                    rmax = fmaxf(rmax, s);
                }
                #pragma unroll
                for (int md = 1; md < 16; md <<= 1)
                    rmax = fmaxf(rmax, __shfl_xor(rmax, md));
                float rsum = 0.f;
                #pragma unroll
                for (int nt = 0; nt < 4; ++nt) {
                    float e = __expf(sv[nt] - rmax);
                    sv[nt] = e;
                    rsum += e;
                }
                #pragma unroll
                for (int md = 1; md < 16; md <<= 1)
                    rsum += __shfl_xor(rsum, md);
                const float inv = 1.f / rsum;
                #pragma unroll
                for (int nt = 0; nt < 4; ++nt)
                    *(f16*)((char*)QPs + swz64(q, (nt * 16 + l15) * 2)) = (f16)(sv[nt] * inv);
            }
        }
        __syncthreads();

        {
            const int pmt = wave >> 1;
            const int pnh = wave & 1;
            f32x4 oacc[2];
            oacc[0] = {0.f, 0.f, 0.f, 0.f};
            oacc[1] = {0.f, 0.f, 0.f, 0.f};
            half8 pa[2];
            #pragma unroll
            for (int ks = 0; ks < 2; ++ks)
                pa[ks] = *(const half8*)((char*)QPs + swz64(pmt * 16 + l15, (ks * 32 + lg * 8) * 2));
            #pragma unroll
            for (int nt2 = 0; nt2 < 2; ++nt2) {
                const int nt = pnh * 2 + nt2;
                #pragma unroll
                for (int ks = 0; ks < 2; ++ks) {
                    half8 vb = *(const half8*)((char*)Vts + swz64(nt * 16 + l15, (ks * 32 + lg * 8) * 2));
                    oacc[nt2] = __builtin_amdgcn_mfma_f32_16x16x32_f16(pa[ks], vb, oacc[nt2], 0, 0, 0);
                }
            }
            #pragma unroll
            for (int r = 0; r < 4; ++r) {
                const int q = pmt * 16 + lg * 4 + r;
                if (q < TOK) {
                    #pragma unroll
                    for (int nt2 = 0; nt2 < 2; ++nt2)
                        out[((size_t)w * TOK + q) * 512 + h * 64 + (pnh * 2 + nt2) * 16 + l15] = oacc[nt2][r];
                }
            }
        }
        __syncthreads();
    }
}

extern "C" void kernel_launch(void* const* d_in, const int* in_sizes, int n_in,
                              void* d_out, int out_size, void* d_ws, size_t ws_size,
                              hipStream_t stream) {
    const float* x  = (const float*)d_in[0];
    const float* wq = (const float*)d_in[1];
    const float* bq = (const float*)d_in[2];
    const float* wk = (const float*)d_in[3];
    const float* bk = (const float*)d_in[4];
    const float* wv = (const float*)d_in[5];
    const float* bv = (const float*)d_in[6];
    const float* pb = (const float*)d_in[7];
    f16*   wbuf = (f16*)d_ws;
    float* out  = (float*)d_out;

    if (ws_size >= WS_NEED) {
        f16* qkv = wbuf + WT_ELEMS;
        prep_wfrag<<<384, 256, 0, stream>>>(wq, wk, wv, wbuf);
        gemm_qkv<<<2048, 512, 0, stream>>>(x, bq, bk, bv, wbuf, qkv);
        attn<<<16384, 64, 0, stream>>>(qkv, pb, out);
    } else {
        prep_weights<<<3072, 256, 0, stream>>>(wq, wk, wv, wbuf);
        swin_attn<<<2048, 512, 0, stream>>>(x, bq, bk, bv, pb, wbuf, out);
    }
}

// Round 7
// 558.082 us; speedup vs baseline: 2.7716x; 2.1468x over previous
//
#include <hip/hip_runtime.h>

typedef _Float16 f16;
typedef _Float16 half8 __attribute__((ext_vector_type(8)));
typedef float f32x4 __attribute__((ext_vector_type(4)));

#define TOK 49
#define HEADS 8

// XOR swizzle: spreads rows across LDS banks
__device__ __forceinline__ int swzX(int row, int kb) { return row * 1024 + (kb ^ ((row & 7) << 4)); }
__device__ __forceinline__ int swz64(int row, int cb) { return row * 128 + (cb ^ ((row & 7) << 4)); }

// ws layout (f16 elems): wf[16 kc][96 ntile][64 lane][8] at 0 (fragment-ordered
// weights, 1.5MB); QKV[2048 win][24 cb][64][64] PLAIN row-major at 786432.
// Q/K tiles: [tok][ch]; V tiles transposed: [ch][tok].
#define WT_ELEMS   786432
#define WS_NEED    404226048ull   // (786432 + 201326592) * 2 bytes

// --------- fragment-ordered weight prep: B-frag = contiguous [ntile][lane][8] ----
// wf[((kc*96 + ntile)*64 + lane)*8 + e] = w_m[k*512 + nloc]
//   n = ntile*16 + (lane&15), m = n>>9, nloc = n&511, k = kc*32 + (lane>>4)*8 + e
__global__ void prep_wfrag(const float* __restrict__ wq,
                           const float* __restrict__ wk,
                           const float* __restrict__ wv,
                           f16* __restrict__ wf) {
    int gid = blockIdx.x * 256 + threadIdx.x;   // 0 .. 98303
    int kc   = gid / 6144;
    int rem  = gid % 6144;
    int nt   = rem >> 6;
    int lane = rem & 63;
    int n    = nt * 16 + (lane & 15);
    int m    = n >> 9;
    int nloc = n & 511;
    int k0   = kc * 32 + (lane >> 4) * 8;
    const float* w = (m == 0) ? wq : (m == 1) ? wk : wv;
    half8 h;
    #pragma unroll
    for (int e = 0; e < 8; ++e) h[e] = (f16)w[(size_t)(k0 + e) * 512 + nloc];
    *(half8*)(wf + (size_t)gid * 8) = h;
}

// legacy layout for fused fallback: wt[3][512 n][512 k]
__global__ void prep_weights(const float* __restrict__ wq,
                             const float* __restrict__ wk,
                             const float* __restrict__ wv,
                             f16* __restrict__ wt) {
    int gid = blockIdx.x * 256 + threadIdx.x;
    int m   = gid >> 18;
    int rem = gid & 262143;
    int n   = rem >> 9;
    int k   = rem & 511;
    const float* w = (m == 0) ? wq : (m == 1) ? wk : wv;
    wt[gid] = (f16)w[k * 512 + n];
}

// ============================ SPLIT PATH ====================================
// Kernel 1: per-window QKV projection, slab-cooperative (m97-style 2-phase):
// weight slab (48 ntiles x 1KB) double-buffered in LDS; per kc: issue next-slab
// loads -> ds_read frags + 24 MFMA/wave -> store slab -> ONE barrier.
// 2 col-passes of 768; acc[6][4]/wave. Epilogue reuses dead Wbuf (96KB = 12
// plain tiles) -> fully coalesced uint4 copyout.
__global__ __launch_bounds__(512, 1)
void gemm_qkv(const float* __restrict__ x,
              const float* __restrict__ bqv,
              const float* __restrict__ bkv,
              const float* __restrict__ bvv,
              const f16* __restrict__ wf,
              f16* __restrict__ qkv) {
    __shared__ f16 Xs[50 * 512];       // 50KB swizzled; row 49 zero
    __shared__ f16 Wbuf[2][24576];     // 2 x 48KB slab; epilogue: 12-tile staging

    const int win  = blockIdx.x;
    const int bb   = win >> 6;
    const int wy   = (win >> 3) & 7;
    const int wx   = win & 7;
    const int tid  = threadIdx.x;
    const int wave = tid >> 6;        // 0..7
    const int lane = tid & 63;
    const int l15  = lane & 15;
    const int lg   = lane >> 4;

    // ---- stage X window -> LDS f16 (swizzled); row 49 zeroed ----
    #pragma unroll
    for (int it = 0; it < 7; ++it) {
        int idx = it * 512 + tid;                 // vec8 slots, 3200 total
        if (idx < 3200) {
            int elem = idx * 8;
            int m = elem >> 9;
            int k = elem & 511;
            half8 h = {(f16)0, (f16)0, (f16)0, (f16)0, (f16)0, (f16)0, (f16)0, (f16)0};
            if (m < TOK) {
                int i = m / 7, j = m - i * 7;
                const float* src = x + (((size_t)(bb * 56 + wy * 7 + i)) * 56 + (wx * 7 + j)) * 512 + k;
                float4 f0 = ((const float4*)src)[0];
                float4 f1 = ((const float4*)src)[1];
                h[0] = (f16)f0.x; h[1] = (f16)f0.y; h[2] = (f16)f0.z; h[3] = (f16)f0.w;
                h[4] = (f16)f1.x; h[5] = (f16)f1.y; h[6] = (f16)f1.z; h[7] = (f16)f1.w;
            }
            *(half8*)((char*)Xs + swzX(m, k * 2)) = h;
        }
    }

    int rowA[4];
    #pragma unroll
    for (int mt = 0; mt < 4; ++mt) {
        int rr = mt * 16 + l15;
        rowA[mt] = (rr < TOK) ? rr : TOK;         // clamp pad rows to zero row 49
    }

    for (int p = 0; p < 2; ++p) {
        // ---- pre-stage slab (p, kc=0) into Wbuf[0] ----
        {
            const f16* slab = wf + (size_t)(p * 48) * 512;
            #pragma unroll
            for (int i = 0; i < 6; ++i) {
                int c = i * 512 + tid;            // 3072 chunks of 16B
                uint4 t = *(const uint4*)(slab + (size_t)c * 8);
                *(uint4*)(&Wbuf[0][(size_t)c * 8]) = t;
            }
        }
        __syncthreads();   // (also covers Xs staging visibility on p==0)

        f32x4 acc[6][4];
        #pragma unroll
        for (int j = 0; j < 6; ++j)
            #pragma unroll
            for (int mt = 0; mt < 4; ++mt)
                acc[j][mt] = {0.f, 0.f, 0.f, 0.f};

        int cur = 0;
        for (int kc = 0; kc < 16; ++kc) {
            // issue next-slab global loads FIRST (latency hides under compute)
            uint4 L[6];
            if (kc < 15) {
                const f16* slab = wf + ((size_t)(kc + 1) * 96 + p * 48) * 512;
                #pragma unroll
                for (int i = 0; i < 6; ++i)
                    L[i] = *(const uint4*)(slab + (size_t)(i * 512 + tid) * 8);
            }
            // compute on Wbuf[cur]
            half8 a[4];
            #pragma unroll
            for (int mt = 0; mt < 4; ++mt)
                a[mt] = *(const half8*)((char*)Xs + swzX(rowA[mt], kc * 64 + lg * 16));
            const char* wb = (const char*)&Wbuf[cur][0];
            #pragma unroll
            for (int j = 0; j < 6; ++j) {
                half8 b = *(const half8*)(wb + ((6 * wave + j) * 64 + lane) * 16);
                #pragma unroll
                for (int mt = 0; mt < 4; ++mt)
                    acc[j][mt] = __builtin_amdgcn_mfma_f32_16x16x32_f16(a[mt], b, acc[j][mt], 0, 0, 0);
            }
            // store next slab, one barrier per kc
            if (kc < 15) {
                #pragma unroll
                for (int i = 0; i < 6; ++i)
                    *(uint4*)(&Wbuf[cur ^ 1][(size_t)(i * 512 + tid) * 8]) = L[i];
            }
            __syncthreads();
            cur ^= 1;
        }

        // ---- epilogue: acc -> plain tiles staged in (dead) Wbuf, then copyout ----
        f16* stg = &Wbuf[0][0];                   // 96KB = 12 tiles x 8KB
        #pragma unroll
        for (int j = 0; j < 6; ++j) {
            const int ntl = 6 * wave + j;         // pass-local ntile 0..47
            const int ntg = p * 48 + ntl;         // global ntile 0..95
            const int mat = ntg >> 5;             // 0=Q 1=K 2=V
            const int tl  = ntl >> 2;             // pass-local tile 0..11
            const int ch  = (ntl & 3) * 16 + l15; // in-tile channel 0..63
            const float* bias = (mat == 0) ? bqv : (mat == 1) ? bkv : bvv;
            const float bs = bias[(ntg * 16 + l15) & 511];
            if (mat < 2) {
                // plain [tok][ch]
                #pragma unroll
                for (int mt = 0; mt < 4; ++mt) {
                    const int t0 = mt * 16 + lg * 4;
                    #pragma unroll
                    for (int r = 0; r < 4; ++r)
                        stg[tl * 4096 + (t0 + r) * 64 + ch] = (f16)(acc[j][mt][r] + bs);
                }
            } else {
                // V transposed [ch][tok]
                #pragma unroll
                for (int mt = 0; mt < 4; ++mt) {
                    const int t0 = mt * 16 + lg * 4;
                    #pragma unroll
                    for (int r = 0; r < 4; ++r)
                        stg[tl * 4096 + ch * 64 + t0 + r] = (f16)(acc[j][mt][r] + bs);
                }
            }
        }
        __syncthreads();
        // coalesced copyout: 96KB -> qkv tiles 12p..12p+11
        f16* dst = qkv + ((size_t)win * 24 + 12 * p) * 4096;
        #pragma unroll
        for (int i = 0; i < 12; ++i) {
            int c = i * 512 + tid;                // 6144 chunks of 16B
            uint4 t = *(const uint4*)(stg + (size_t)c * 8);
            *(uint4*)(dst + (size_t)c * 8) = t;
        }
        __syncthreads();                          // before next pass re-stages Wbuf
    }
}

// Kernel 2: one wave per (window, head). PLAIN tiles -> all Q/K/V MFMA frags
// load DIRECT from global (coalesced 64B sectors, each tile read once).
// LDS only holds P (8KB) -> high occupancy.
__global__ __launch_bounds__(64)
void attn(const f16* __restrict__ qkv,
          const float* __restrict__ pos_bias,
          float* __restrict__ out) {
    __shared__ f16 Ps[64 * 64];    // 8KB

    const int blk  = blockIdx.x;          // win*8 + head
    const int win  = blk >> 3;
    const int head = blk & 7;
    const int lane = threadIdx.x;
    const int l15  = lane & 15;
    const int lg   = lane >> 4;

    const f16* gQ = qkv + ((size_t)win * 24 + head) * 4096;
    const f16* gK = gQ + 8 * 4096;
    const f16* gV = gQ + 16 * 4096;

    const float scale = 0.044194173824159216f;   // 1/sqrt(512)
    const float* pb = pos_bias + head * TOK * TOK;

    // direct global frag loads: lane l15 -> row, lg*8 -> col chunk
    half8 qa[4][2], kb[4][2];
    #pragma unroll
    for (int mt = 0; mt < 4; ++mt)
        #pragma unroll
        for (int ks = 0; ks < 2; ++ks)
            qa[mt][ks] = *(const half8*)(gQ + (mt * 16 + l15) * 64 + ks * 32 + lg * 8);
    #pragma unroll
    for (int nt = 0; nt < 4; ++nt)
        #pragma unroll
        for (int ks = 0; ks < 2; ++ks)
            kb[nt][ks] = *(const half8*)(gK + (nt * 16 + l15) * 64 + ks * 32 + lg * 8);

    #pragma unroll
    for (int mt = 0; mt < 4; ++mt) {
        f32x4 sacc[4];
        #pragma unroll
        for (int nt = 0; nt < 4; ++nt) sacc[nt] = {0.f, 0.f, 0.f, 0.f};
        #pragma unroll
        for (int nt = 0; nt < 4; ++nt)
            #pragma unroll
            for (int ks = 0; ks < 2; ++ks)
                sacc[nt] = __builtin_amdgcn_mfma_f32_16x16x32_f16(qa[mt][ks], kb[nt][ks], sacc[nt], 0, 0, 0);

        #pragma unroll
        for (int r = 0; r < 4; ++r) {
            const int q  = mt * 16 + lg * 4 + r;
            const int qp = (q < TOK) ? q : 0;
            float sv[4];
            float rmax = -3.4028235e38f;
            #pragma unroll
            for (int nt = 0; nt < 4; ++nt) {
                const int t2 = nt * 16 + l15;
                const int tp = (t2 < TOK) ? t2 : 0;
                float s = sacc[nt][r] * scale + pb[qp * TOK + tp];
                const bool valid = (q < TOK) && (t2 < TOK) && (t2 != q);
                s = valid ? s : -3.4028235e38f;   // eye-mask = finfo.min semantics
                sv[nt] = s;
                rmax = fmaxf(rmax, s);
            }
            #pragma unroll
            for (int md = 1; md < 16; md <<= 1)
                rmax = fmaxf(rmax, __shfl_xor(rmax, md));
            float rsum = 0.f;
            #pragma unroll
            for (int nt = 0; nt < 4; ++nt) {
                float e = __expf(sv[nt] - rmax);
                sv[nt] = e;
                rsum += e;
            }
            #pragma unroll
            for (int md = 1; md < 16; md <<= 1)
                rsum += __shfl_xor(rsum, md);
            const float inv = 1.f / rsum;
            #pragma unroll
            for (int nt = 0; nt < 4; ++nt)
                *(f16*)((char*)Ps + swz64(q, (nt * 16 + l15) * 2)) = (f16)(sv[nt] * inv);
        }
    }

    // ---- O = P V : V^T frags direct from global (kb registers now dead) ----
    half8 vb[4][2];
    #pragma unroll
    for (int ct = 0; ct < 4; ++ct)
        #pragma unroll
        for (int ks = 0; ks < 2; ++ks)
            vb[ct][ks] = *(const half8*)(gV + (ct * 16 + l15) * 64 + ks * 32 + lg * 8);

    #pragma unroll
    for (int mt = 0; mt < 4; ++mt) {
        half8 pa[2];
        #pragma unroll
        for (int ks = 0; ks < 2; ++ks)
            pa[ks] = *(const half8*)((char*)Ps + swz64(mt * 16 + l15, (ks * 32 + lg * 8) * 2));
        f32x4 oacc[4];
        #pragma unroll
        for (int ct = 0; ct < 4; ++ct) oacc[ct] = {0.f, 0.f, 0.f, 0.f};
        #pragma unroll
        for (int ct = 0; ct < 4; ++ct)
            #pragma unroll
            for (int ks = 0; ks < 2; ++ks)
                oacc[ct] = __builtin_amdgcn_mfma_f32_16x16x32_f16(pa[ks], vb[ct][ks], oacc[ct], 0, 0, 0);
        #pragma unroll
        for (int r = 0; r < 4; ++r) {
            const int q = mt * 16 + lg * 4 + r;
            if (q < TOK) {
                #pragma unroll
                for (int ct = 0; ct < 4; ++ct)
                    out[((size_t)win * TOK + q) * 512 + head * 64 + ct * 16 + l15] = oacc[ct][r];
            }
        }
    }
}

// ============================ FUSED FALLBACK ================================
__global__ __launch_bounds__(512, 4)
void swin_attn(const float* __restrict__ x,
               const float* __restrict__ bqv,
               const float* __restrict__ bkv,
               const float* __restrict__ bvv,
               const float* __restrict__ pos_bias,
               const f16* __restrict__ wt,
               float* __restrict__ out) {
    __shared__ f16 Xs [50 * 512];
    __shared__ f16 QPs[64 * 64];
    __shared__ f16 Ks [64 * 64];
    __shared__ f16 Vts[64 * 64];

    const int w    = blockIdx.x;
    const int bb   = w >> 6;
    const int wy   = (w >> 3) & 7;
    const int wx   = w & 7;
    const int tid  = threadIdx.x;
    const int wave = tid >> 6;
    const int lane = tid & 63;
    const int l15  = lane & 15;
    const int lg   = lane >> 4;
    const int mh   = wave & 1;
    const int wi   = wave >> 1;

    #pragma unroll
    for (int it = 0; it < 7; ++it) {
        int idx = it * 512 + tid;
        int elem = idx * 8;
        if (elem < 50 * 512) {
            int m = elem >> 9;
            int k = elem & 511;
            half8 h = {(f16)0, (f16)0, (f16)0, (f16)0, (f16)0, (f16)0, (f16)0, (f16)0};
            if (m < TOK) {
                int i = m / 7, j = m - i * 7;
                const float* src = x + (((size_t)(bb * 56 + wy * 7 + i)) * 56 + (wx * 7 + j)) * 512 + k;
                float4 f0 = ((const float4*)src)[0];
                float4 f1 = ((const float4*)src)[1];
                h[0] = (f16)f0.x; h[1] = (f16)f0.y; h[2] = (f16)f0.z; h[3] = (f16)f0.w;
                h[4] = (f16)f1.x; h[5] = (f16)f1.y; h[6] = (f16)f1.z; h[7] = (f16)f1.w;
            }
            *(half8*)((char*)Xs + swzX(m, k * 2)) = h;
        }
    }
    __syncthreads();

    const float scale = 0.044194173824159216f;

    for (int h = 0; h < HEADS; ++h) {
        f32x4 aQ[2], aK[2], aV[2];
        #pragma unroll
        for (int mt = 0; mt < 2; ++mt) {
            aQ[mt] = {0.f, 0.f, 0.f, 0.f};
            aK[mt] = {0.f, 0.f, 0.f, 0.f};
            aV[mt] = {0.f, 0.f, 0.f, 0.f};
        }
        const int ncol = h * 64 + wi * 16 + l15;
        const f16* pQ = wt + (size_t)(ncol) * 512;
        const f16* pK = wt + (size_t)(512 + ncol) * 512;
        const f16* pV = wt + (size_t)(1024 + ncol) * 512;
        const int r0 = mh * 32 + l15;
        const int r1 = mh * 32 + 16 + l15;
        const int rp0 = (r0 < TOK) ? r0 : 49;
        const int rp1 = (r1 < TOK) ? r1 : 49;
        #pragma unroll
        for (int ks = 0; ks < 16; ++ks) {
            const int kk = ks * 32 + lg * 8;
            half8 a0 = *(const half8*)((char*)Xs + swzX(rp0, kk * 2));
            half8 a1 = *(const half8*)((char*)Xs + swzX(rp1, kk * 2));
            half8 fQ = *(const half8*)(pQ + kk);
            half8 fK = *(const half8*)(pK + kk);
            half8 fV = *(const half8*)(pV + kk);
            aQ[0] = __builtin_amdgcn_mfma_f32_16x16x32_f16(a0, fQ, aQ[0], 0, 0, 0);
            aQ[1] = __builtin_amdgcn_mfma_f32_16x16x32_f16(a1, fQ, aQ[1], 0, 0, 0);
            aK[0] = __builtin_amdgcn_mfma_f32_16x16x32_f16(a0, fK, aK[0], 0, 0, 0);
            aK[1] = __builtin_amdgcn_mfma_f32_16x16x32_f16(a1, fK, aK[1], 0, 0, 0);
            aV[0] = __builtin_amdgcn_mfma_f32_16x16x32_f16(a0, fV, aV[0], 0, 0, 0);
            aV[1] = __builtin_amdgcn_mfma_f32_16x16x32_f16(a1, fV, aV[1], 0, 0, 0);
        }

        const float biasQ = bqv[ncol];
        const float biasK = bkv[ncol];
        const float biasV = bvv[ncol];
        const int nloc = wi * 16 + l15;
        #pragma unroll
        for (int mt = 0; mt < 2; ++mt) {
            const int m0 = mh * 32 + mt * 16 + lg * 4;
            #pragma unroll
            for (int r = 0; r < 4; ++r) {
                *(f16*)((char*)QPs + swz64(m0 + r, nloc * 2)) = (f16)(aQ[mt][r] + biasQ);
                *(f16*)((char*)Ks  + swz64(m0 + r, nloc * 2)) = (f16)(aK[mt][r] + biasK);
            }
            #pragma unroll
            for (int r = 0; r < 4; ++r)
                *(f16*)((char*)Vts + swz64(nloc, (m0 + r) * 2)) = (f16)(aV[mt][r] + biasV);
        }
        __syncthreads();

        if (wave < 4) {
            f32x4 sacc[4];
            #pragma unroll
            for (int nt = 0; nt < 4; ++nt) sacc[nt] = {0.f, 0.f, 0.f, 0.f};
            half8 qa[2];
            #pragma unroll
            for (int ks = 0; ks < 2; ++ks)
                qa[ks] = *(const half8*)((char*)QPs + swz64(wave * 16 + l15, (ks * 32 + lg * 8) * 2));
            #pragma unroll
            for (int nt = 0; nt < 4; ++nt) {
                #pragma unroll
                for (int ks = 0; ks < 2; ++ks) {
                    half8 kb = *(const half8*)((char*)Ks + swz64(nt * 16 + l15, (ks * 32 + lg * 8) * 2));
                    sacc[nt] = __builtin_amdgcn_mfma_f32_16x16x32_f16(qa[ks], kb, sacc[nt], 0, 0, 0);
                }
            }
            const float* pb = pos_bias + h * TOK * TOK;
            #pragma unroll
            for (int r = 0; r < 4; ++r) {
                const int q  = wave * 16 + lg * 4 + r;
                const int qp = (q < TOK) ? q : 0;
                float sv[4];
                float rmax = -3.4028235e38f;
                #pragma unroll
                for (int nt = 0; nt < 4; ++nt) {
                    const int t2 = nt * 16 + l15;
                    const int tp = (t2 < TOK) ? t2 : 0;
                    float s = sacc[nt][r] * scale + pb[qp * TOK + tp];
                    const bool valid = (q < TOK) && (t2 < TOK) && (t2 != q);
                    s = valid ? s : -3.4028235e38f;
                    sv[nt] = s;
                    rmax = fmaxf(rmax, s);
                }
                #pragma unroll
                for (int md = 1; md < 16; md <<= 1)
                    rmax = fmaxf(rmax, __shfl_xor(rmax, md));
                float rsum = 0.f;
                #pragma unroll
                for (int nt = 0; nt < 4; ++nt) {
                    float e = __expf(sv[nt] - rmax);
                    sv[nt] = e;
                    rsum += e;
                }
                #pragma unroll
                for (int md = 1; md < 16; md <<= 1)
                    rsum += __shfl_xor(rsum, md);
                const float inv = 1.f / rsum;
                #pragma unroll
                for (int nt = 0; nt < 4; ++nt)
                    *(f16*)((char*)QPs + swz64(q, (nt * 16 + l15) * 2)) = (f16)(sv[nt] * inv);
            }
        }
        __syncthreads();

        {
            const int pmt = wave >> 1;
            const int pnh = wave & 1;
            f32x4 oacc[2];
            oacc[0] = {0.f, 0.f, 0.f, 0.f};
            oacc[1] = {0.f, 0.f, 0.f, 0.f};
            half8 pa[2];
            #pragma unroll
            for (int ks = 0; ks < 2; ++ks)
                pa[ks] = *(const half8*)((char*)QPs + swz64(pmt * 16 + l15, (ks * 32 + lg * 8) * 2));
            #pragma unroll
            for (int nt2 = 0; nt2 < 2; ++nt2) {
                const int nt = pnh * 2 + nt2;
                #pragma unroll
                for (int ks = 0; ks < 2; ++ks) {
                    half8 vb = *(const half8*)((char*)Vts + swz64(nt * 16 + l15, (ks * 32 + lg * 8) * 2));
                    oacc[nt2] = __builtin_amdgcn_mfma_f32_16x16x32_f16(pa[ks], vb, oacc[nt2], 0, 0, 0);
                }
            }
            #pragma unroll
            for (int r = 0; r < 4; ++r) {
                const int q = pmt * 16 + lg * 4 + r;
                if (q < TOK) {
                    #pragma unroll
                    for (int nt2 = 0; nt2 < 2; ++nt2)
                        out[((size_t)w * TOK + q) * 512 + h * 64 + (pnh * 2 + nt2) * 16 + l15] = oacc[nt2][r];
                }
            }
        }
        __syncthreads();
    }
}

extern "C" void kernel_launch(void* const* d_in, const int* in_sizes, int n_in,
                              void* d_out, int out_size, void* d_ws, size_t ws_size,
                              hipStream_t stream) {
    const float* x  = (const float*)d_in[0];
    const float* wq = (const float*)d_in[1];
    const float* bq = (const float*)d_in[2];
    const float* wk = (const float*)d_in[3];
    const float* bk = (const float*)d_in[4];
    const float* wv = (const float*)d_in[5];
    const float* bv = (const float*)d_in[6];
    const float* pb = (const float*)d_in[7];
    f16*   wbuf = (f16*)d_ws;
    float* out  = (float*)d_out;

    if (ws_size >= WS_NEED) {
        f16* qkv = wbuf + WT_ELEMS;
        prep_wfrag<<<384, 256, 0, stream>>>(wq, wk, wv, wbuf);
        gemm_qkv<<<2048, 512, 0, stream>>>(x, bq, bk, bv, wbuf, qkv);
        attn<<<16384, 64, 0, stream>>>(qkv, pb, out);
    } else {
        prep_weights<<<3072, 256, 0, stream>>>(wq, wk, wv, wbuf);
        swin_attn<<<2048, 512, 0, stream>>>(x, bq, bk, bv, pb, wbuf, out);
    }
}